// Round 9
// baseline (138.418 us; speedup 1.0000x reference)
//
#include <hip/hip_runtime.h>
#include <cstdint>

#define BB 4
#define RR 512
#define CC 80
#define KK 100
#define NMS_TH 0.3f
#define SCORE_TH 0.1f
#define DWH_CLIP 4.135166556742356f

typedef unsigned short u16;
typedef unsigned int u32;
typedef unsigned long long u64;

__device__ __forceinline__ u32 f32_sortable(float f) {
  u32 u = __float_as_uint(f);
  u32 mask = (u32)((int)u >> 31) | 0x80000000u;
  return u ^ mask;
}
__device__ __forceinline__ float sortable_to_f32(u32 s) {
  u32 u = (s & 0x80000000u) ? (s ^ 0x80000000u) : ~s;
  return __uint_as_float(u);
}

__device__ __forceinline__ void sort128(u64* smallkeys, int tid) {
  u64 v = (tid < 128) ? smallkeys[tid] : ~0ull;
  const u32 t = (u32)tid;
  for (u32 kk = 2; kk <= 128; kk <<= 1) {
    for (u32 j = kk >> 1; j > 0; j >>= 1) {
      if (j >= 64) {
        if (tid < 128) smallkeys[t] = v;
        __syncthreads();
        u64 p = (tid < 128) ? smallkeys[t ^ j] : ~0ull;
        __syncthreads();
        if (tid < 128) {
          bool up = ((t & kk) == 0);
          bool lower = ((t & j) == 0);
          bool takemin = (up == lower);
          bool pless = (p < v);
          v = (takemin == pless) ? p : v;
        }
      } else if (tid < 128) {
        u64 p = __shfl_xor(v, (int)j);
        bool up = ((t & kk) == 0);
        bool lower = ((t & j) == 0);
        bool takemin = (up == lower);
        bool pless = (p < v);
        v = (takemin == pless) ? p : v;
      }
    }
  }
  if (tid < 128) smallkeys[t] = v;
  __syncthreads();
}

// One block of 512 per (b,c): register-bitonic sort (0 barriers), decode,
// lazy greedy NMS (precomputed row-masks, scalar scan chain), emit <=100
// candidates. The last block per image (atomic counter) then runs the
// per-image radix-select top-100 in the same launch.
// Certain-test (validated R4-R8): q > TH <=> inter*(1+TH)/TH > ai+aj+1e-9
// in reals; band +-2e-6 >> rounding error ~3e-7; exact IEEE-divide fallback.
__global__ __launch_bounds__(512) void nms_topk(
    const float* __restrict__ rois,     // [B,R,4]
    const float* __restrict__ scores,   // [B*R, C+1]
    const float* __restrict__ deltas,   // [B*R, (C+1)*4]
    const int*   __restrict__ im_hw,    // [B,2]
    u32*   __restrict__ done_cnt,       // [B]
    u64*   __restrict__ cand_key,       // [B*C, K]
    float4* __restrict__ cand_box,      // [B*C, K]
    float* __restrict__ out)            // [B, K, 6]
{
#pragma clang fp contract(off)
  const int bc = blockIdx.x;
  const int b = bc / CC, c = bc % CC;
  const int tid = threadIdx.x;
  const int lane = tid & 63, wv = tid >> 6;

  __shared__ __align__(16) char pool[42240];
  float4* box_s = (float4*)pool;                 //  8192 B
  float*  sco_s = (float*)(pool + 8192);         //  2048 B
  u64*    rmk_w = (u64*)(pool + 10240);          //  4096 B [8][64]
  float4* kbox  = (float4*)(pool + 14336);       //  1600 B
  float*  ksc   = (float*)(pool + 15936);        //   400 B
  float*  karea = (float*)(pool + 16336);        //   400 B
  __shared__ u64 supacc_arr[8];
  __shared__ int nkept_s, lastflag;

  const float fh = (float)im_hw[b * 2 + 0] - 1.0f;
  const float fw = (float)im_hw[b * 2 + 1] - 1.0f;

  // ---- stage raw scores ----
  sco_s[tid] = scores[(b * RR + tid) * (CC + 1) + (c + 1)];
  __syncthreads();

  // ---- register bitonic sort: 8 elems/lane (elem = r*64+lane), 0 barriers.
  // j>=64 -> in-register partner (r ^ (j>>6)); j<64 -> shfl_xor.
  u64 k[8];
  #pragma unroll
  for (int r = 0; r < 8; ++r) {
    const int e = r * 64 + lane;
    k[r] = ((u64)(~f32_sortable(sco_s[e])) << 32) | (u32)e;  // score desc, idx asc
  }
  #pragma unroll
  for (u32 kk2 = 2; kk2 <= 512; kk2 <<= 1) {
    #pragma unroll
    for (u32 j = 256; j > 0; j >>= 1) {
      if (j > (kk2 >> 1)) continue;
      if (j >= 64) {
        const int dj = (int)(j >> 6);
        #pragma unroll
        for (int r = 0; r < 8; ++r) {
          if ((r & dj) == 0) {
            const int r2 = r | dj;
            const bool up = (((u32)(r * 64) & kk2) == 0);
            u64 a = k[r], b2 = k[r2];
            const bool sw = up ? (a > b2) : (a < b2);
            if (sw) { k[r] = b2; k[r2] = a; }
          }
        }
      } else {
        #pragma unroll
        for (int r = 0; r < 8; ++r) {
          u64 p = __shfl_xor(k[r], (int)j);
          const u32 e = (u32)(r * 64) + (u32)lane;
          const bool up = ((e & kk2) == 0);
          const bool lower = (((u32)lane & j) == 0);
          const bool takemin = (up == lower);
          const bool pless = (p < k[r]);
          k[r] = (takemin == pless) ? p : k[r];
        }
      }
    }
  }
  __syncthreads();   // raw sco_s reads done (all waves)

  // ---- decode: thread tid = sorted element tid = this wave's reg wv ----
  {
    u64 kv = k[0];
    #pragma unroll
    for (int r = 1; r < 8; ++r) if (wv == r) kv = k[r];
    const int rr = (int)(kv & 0xFFFFFFFFull);
    const float sc = sortable_to_f32(~(u32)(kv >> 32));   // bit-exact original
    const float4 roi = *(const float4*)&rois[(b * RR + rr) * 4];
    const int base = (b * RR + rr) * (CC + 1) + (c + 1);
    const float4 d = *(const float4*)&deltas[base * 4];

    float w  = roi.z - roi.x;
    float h  = roi.w - roi.y;
    float cx = roi.x + 0.5f * w;
    float cy = roi.y + 0.5f * h;
    float dw = fminf(d.z, DWH_CLIP);
    float dh = fminf(d.w, DWH_CLIP);
    float pcx = d.x * w + cx;
    float pcy = d.y * h + cy;
    float pw = w * expf(dw);
    float ph = h * expf(dh);
    float hx = 0.5f * pw, hy = 0.5f * ph;
    float x1 = fminf(fmaxf(pcx - hx, 0.0f), fw);
    float y1 = fminf(fmaxf(pcy - hy, 0.0f), fh);
    float x2 = fminf(fmaxf(pcx + hx, 0.0f), fw);
    float y2 = fminf(fmaxf(pcy + hy, 0.0f), fh);

    box_s[tid] = make_float4(x1, y1, x2, y2);
    sco_s[tid] = sc;
    if (tid == 0) nkept_s = 0;
  }
  __syncthreads();

  // ---- rmk precompute: wave w -> chunk w row-masks, uniform LDS reads ----
  {
    const float4 bxr = box_s[wv * 64 + lane];
    const float ar = (bxr.z - bxr.x) * (bxr.w - bxr.y);
    const float areps = ar + 1e-9f;
    u64 myrow = 0;
    for (int j = 0; j < 64; ++j) {
      const float4 cb = box_s[wv * 64 + j];               // broadcast
      const float ca = (cb.z - cb.x) * (cb.w - cb.y);
      float iw = fminf(bxr.z, cb.z) - fmaxf(bxr.x, cb.x);
      float ih = fminf(bxr.w, cb.w) - fmaxf(bxr.y, cb.y);
      iw = fmaxf(iw, 0.0f);
      ih = fmaxf(ih, 0.0f);
      const float inter = iw * ih;
      const float S = ca + areps;
      bool yes = inter * 4.3333247f > S;                  // 13/3*(1-2e-6)
      const bool no = inter * 4.3333420f < S;             // 13/3*(1+2e-6)
      if (__any(!(yes || no))) {                          // ~never taken
        const float denom = ((ca + ar) - inter) + 1e-9f;  // exact ref order
        const bool pe = inter / denom > NMS_TH;
        yes = (yes || no) ? yes : pe;
      }
      myrow |= yes ? (1ull << j) : 0ull;
    }
    myrow &= ~((2ull << lane) - 1ull);                    // only cols > row
    rmk_w[wv * 64 + lane] = myrow;
  }
  __syncthreads();

  // ---- lazy greedy scan over chunks ----
  int nk = 0;
  for (int w = 0; w < 8 && nk < KK; ++w) {
    // kept-suppression: waves split kept range
    {
      const float4 bxc = box_s[w * 64 + lane];
      const float ar = (bxc.z - bxc.x) * (bxc.w - bxc.y);
      const float areps = ar + 1e-9f;
      bool sup = false;
      for (int kx = wv; kx < nk; kx += 8) {
        const float4 kb = kbox[kx];                       // broadcast
        const float ka = karea[kx];
        float iw = fminf(bxc.z, kb.z) - fmaxf(bxc.x, kb.x);
        float ih = fminf(bxc.w, kb.w) - fmaxf(bxc.y, kb.y);
        iw = fmaxf(iw, 0.0f);
        ih = fmaxf(ih, 0.0f);
        const float inter = iw * ih;
        const float S = ka + areps;
        bool yes = inter * 4.3333247f > S;
        const bool no = inter * 4.3333420f < S;
        if (__any(!(yes || no))) {                        // ~never taken
          const float denom = ((ka + ar) - inter) + 1e-9f;
          const bool pe = inter / denom > NMS_TH;
          yes = (yes || no) ? yes : pe;
        }
        sup = sup || yes;
      }
      const u64 bal = __ballot(sup);
      if (lane == 0) supacc_arr[wv] = bal;
    }
    __syncthreads();

    // serial scan (wave 0): scalar chain (ffs + readlane + and)
    if (wv == 0) {
      u64 sup = supacc_arr[0];
      #pragma unroll
      for (int ww = 1; ww < 8; ++ww) sup |= supacc_arr[ww];
      const u64 rm = rmk_w[w * 64 + lane];
      const u32 rlo = (u32)rm, rhi = (u32)(rm >> 32);
      u64 todo = __ballot(sco_s[w * 64 + lane] > SCORE_TH) & ~sup;
      int nkl = nk;
      while (todo) {
        const int i = __ffsll((long long)todo) - 1;       // best remaining
        if (lane == 0) {
          const float4 kb = box_s[w * 64 + i];
          kbox[nkl] = kb;
          ksc[nkl] = sco_s[w * 64 + i];
          karea[nkl] = (kb.z - kb.x) * (kb.w - kb.y);
        }
        ++nkl;
        if (nkl >= KK) break;
        const u32 rl = (u32)__builtin_amdgcn_readlane((int)rlo, i);
        const u32 rh = (u32)__builtin_amdgcn_readlane((int)rhi, i);
        todo &= ~((2ull << i) - 1ull);                    // clear bits <= i
        todo &= ~(((u64)rh << 32) | rl);
      }
      if (lane == 0) nkept_s = nkl;
    }
    __syncthreads();
    nk = nkept_s;
  }

  // ---- emit candidates (pads unique, score = -1e9 = reference NEG) ----
  if (tid < KK) {
    const int kx = tid;
    u64 kv; float4 obx;
    if (kx < nk) {
      kv = ((u64)(~f32_sortable(ksc[kx])) << 32) | ((u64)(u32)c << 16) | (u32)kx;
      obx = kbox[kx];
    } else {
      kv = ((u64)(~f32_sortable(-1e9f)) << 32) | ((u64)(u32)c << 16) | (u32)kx;
      obx = make_float4(0.f, 0.f, 0.f, 0.f);
    }
    cand_key[bc * KK + kx] = kv;
    cand_box[bc * KK + kx] = obx;
  }

  // ---- last block per image runs the top-k ----
  __threadfence();
  if (tid == 0) {
    const u32 old = atomicAdd(&done_cnt[b], 1u);
    lastflag = (old == CC - 1) ? 1 : 0;
  }
  __syncthreads();
  if (!lastflag) return;
  __threadfence();

  // ===== top-k phase (512 threads), LDS pool re-aliased =====
  const int N = CC * KK;                 // 8000
  const u64* __restrict__ keys_g = cand_key + (size_t)b * N;
  u16* candA = (u16*)pool;               // 16000 B
  u16* candB = (u16*)(pool + 16000);     // 16000 B
  u32* whist = (u32*)(pool + 32000);     // [8][256] 8192 B
  u32* bins  = (u32*)(pool + 40192);     // 1024 B
  u64* smallkeys = (u64*)(pool + 41216); // 1024 B
  __shared__ int ncand_s, rank_s, q_s;
  __shared__ u32 cnt_s;

  if (tid == 0) { ncand_s = N; rank_s = KK - 1; }

  u16* cur = candA;
  u16* oth = candB;
  bool first = true;
  int d = 7;
  for (;;) {
    for (int t = tid; t < 8 * 256; t += 512) whist[t] = 0;
    __syncthreads();
    const int nc = first ? N : ncand_s;
    const int sh = d * 8;
    for (int t0 = 0; t0 < nc; t0 += 512) {
      const int t = t0 + tid;
      if (t < nc) {
        const int idx = first ? t : (int)cur[t];
        u32 dig = (u32)((keys_g[idx] >> sh) & 0xFF);
        atomicAdd(&whist[wv * 256 + dig], 1u);
      }
    }
    __syncthreads();
    if (tid < 256) {
      u32 s = 0;
      #pragma unroll
      for (int ww = 0; ww < 8; ++ww) s += whist[ww * 256 + tid];
      bins[tid] = s;
    }
    __syncthreads();
    if (wv == 0) {
      u32 c0 = bins[lane * 4 + 0], c1 = bins[lane * 4 + 1];
      u32 c2 = bins[lane * 4 + 2], c3 = bins[lane * 4 + 3];
      u32 lsum = c0 + c1 + c2 + c3;
      u32 incl = lsum;
      #pragma unroll
      for (int off = 1; off < 64; off <<= 1) {
        u32 v = __shfl_up(incl, off);
        if (lane >= off) incl += v;
      }
      u32 excl = incl - lsum;
      int rk = rank_s;
      u32 s0 = excl, s1 = excl + c0, s2 = s1 + c1, s3 = s2 + c2;
      int q = -1; u32 nr = 0;
      if (rk >= (int)s0 && rk < (int)(s0 + c0)) { q = lane * 4 + 0; nr = rk - s0; }
      else if (rk >= (int)s1 && rk < (int)(s1 + c1)) { q = lane * 4 + 1; nr = rk - s1; }
      else if (rk >= (int)s2 && rk < (int)(s2 + c2)) { q = lane * 4 + 2; nr = rk - s2; }
      else if (rk >= (int)s3 && rk < (int)(s3 + c3)) { q = lane * 4 + 3; nr = rk - s3; }
      if (q >= 0) { q_s = q; rank_s = (int)nr; }
    }
    if (tid == 0) cnt_s = 0;
    __syncthreads();
    const int q = q_s;
    for (int t0 = 0; t0 < nc; t0 += 512) {
      const int t = t0 + tid;
      int idx = 0; bool m = false;
      if (t < nc) {
        idx = first ? t : (int)cur[t];
        m = ((int)((keys_g[idx] >> sh) & 0xFF) == q);
      }
      u64 bal = __ballot(m);
      u32 base = 0;
      if (lane == 0 && bal) base = atomicAdd(&cnt_s, (u32)__popcll(bal));
      base = __shfl(base, 0);
      if (m) oth[base + (u32)__popcll(bal & ((1ull << lane) - 1ull))] = (u16)idx;
    }
    __syncthreads();
    if (tid == 0) ncand_s = (int)cnt_s;
    { u16* tmp = cur; cur = oth; oth = tmp; }
    first = false;
    __syncthreads();
    if (ncand_s <= 128 || d == 0) break;
    --d;
  }

  u64 T;
  const int nc2 = ncand_s;
  if (nc2 == 1) {
    T = keys_g[cur[0]];
  } else {
    if (tid < 128) smallkeys[tid] = (tid < nc2) ? keys_g[cur[tid]] : ~0ull;
    __syncthreads();
    sort128(smallkeys, tid);
    T = smallkeys[rank_s];                 // rank within candidate set
    __syncthreads();
  }

  // gather the exactly-100 keys <= T (wave-aggregated)
  if (tid == 0) cnt_s = 0;
  if (tid < 128) smallkeys[tid] = ~0ull;
  __syncthreads();
  for (int t0 = 0; t0 < N; t0 += 512) {
    const int t = t0 + tid;
    u64 kk = 0; bool m = false;
    if (t < N) { kk = keys_g[t]; m = (kk <= T); }
    u64 bal = __ballot(m);
    u32 base = 0;
    if (lane == 0 && bal) base = atomicAdd(&cnt_s, (u32)__popcll(bal));
    base = __shfl(base, 0);
    if (m) {
      u32 p = base + (u32)__popcll(bal & ((1ull << lane) - 1ull));
      if (p < 128) smallkeys[p] = kk;
    }
  }
  __syncthreads();

  sort128(smallkeys, tid);

  if (tid < KK) {
    const u64 kv = smallkeys[tid];
    const float s = sortable_to_f32(~(u32)(kv >> 32));
    float x1 = 0.f, y1 = 0.f, x2 = 0.f, y2 = 0.f, so = 0.f, cf = -1.0f;
    if (s > -5.0e8f) {                     // valid = top_s > NEG*0.5
      int cc2 = (int)((kv >> 16) & 0xFFFFull);
      int kx = (int)(kv & 0xFFFFull);
      float4 bx = cand_box[((size_t)b * CC + cc2) * KK + kx];
      x1 = bx.x; y1 = bx.y; x2 = bx.z; y2 = bx.w;
      so = s; cf = (float)cc2;
    }
    float* o = out + ((size_t)b * KK + tid) * 6;
    o[0] = x1; o[1] = y1; o[2] = x2; o[3] = y2; o[4] = so; o[5] = cf;
  }
}

extern "C" void kernel_launch(void* const* d_in, const int* in_sizes, int n_in,
                              void* d_out, int out_size, void* d_ws, size_t ws_size,
                              hipStream_t stream) {
  (void)in_sizes; (void)n_in; (void)out_size; (void)ws_size;
  const float* rois   = (const float*)d_in[0];
  const float* scores = (const float*)d_in[1];
  const float* deltas = (const float*)d_in[2];
  const int*   im_hw  = (const int*)d_in[3];

  char* ws = (char*)d_ws;
  u32*    done_cnt = (u32*)ws;                     // 16 B (page-padded)
  u64*    cand_key = (u64*)(ws + 4096);            // 4*80*100*8 = 256,000
  float4* cand_box = (float4*)(ws + 4096 + 256000);// 4*80*100*16= 512,000

  hipMemsetAsync(done_cnt, 0, BB * sizeof(u32), stream);
  nms_topk<<<BB * CC, 512, 0, stream>>>(rois, scores, deltas, im_hw,
                                        done_cnt, cand_key, cand_box,
                                        (float*)d_out);
}

// Round 10
// 117.141 us; speedup vs baseline: 1.1816x; 1.1816x over previous
//
#include <hip/hip_runtime.h>
#include <cstdint>

#define BB 4
#define RR 512
#define CC 80
#define KK 100
#define NMS_TH 0.3f
#define SCORE_TH 0.1f
#define DWH_CLIP 4.135166556742356f

typedef unsigned short u16;
typedef unsigned int u32;
typedef unsigned long long u64;

__device__ __forceinline__ u32 f32_sortable(float f) {
  u32 u = __float_as_uint(f);
  u32 mask = (u32)((int)u >> 31) | 0x80000000u;
  return u ^ mask;
}
__device__ __forceinline__ float sortable_to_f32(u32 s) {
  u32 u = (s & 0x80000000u) ? (s ^ 0x80000000u) : ~s;
  return __uint_as_float(u);
}

__device__ __forceinline__ void sort128(u64* smallkeys, int tid) {
  u64 v = (tid < 128) ? smallkeys[tid] : ~0ull;
  const u32 t = (u32)tid;
  for (u32 kk = 2; kk <= 128; kk <<= 1) {
    for (u32 j = kk >> 1; j > 0; j >>= 1) {
      if (j >= 64) {
        if (tid < 128) smallkeys[t] = v;
        __syncthreads();
        u64 p = (tid < 128) ? smallkeys[t ^ j] : ~0ull;
        __syncthreads();
        if (tid < 128) {
          bool up = ((t & kk) == 0);
          bool lower = ((t & j) == 0);
          bool takemin = (up == lower);
          bool pless = (p < v);
          v = (takemin == pless) ? p : v;
        }
      } else if (tid < 128) {
        u64 p = __shfl_xor(v, (int)j);
        bool up = ((t & kk) == 0);
        bool lower = ((t & j) == 0);
        bool takemin = (up == lower);
        bool pless = (p < v);
        v = (takemin == pless) ? p : v;
      }
    }
  }
  if (tid < 128) smallkeys[t] = v;
  __syncthreads();
}

// One block of 512 per (b,c): LDS-hybrid sort (R8-proven), decode, lazy
// greedy NMS (per-chunk rmk slices, scalar readlane scan chain), emit <=100
// candidates; last block per image runs the radix-select top-100 in-launch.
// Certain-test (validated R4-R9): q > TH <=> inter*(1+TH)/TH > ai+aj+1e-9
// in reals; band +-2e-6 >> rounding error ~3e-7; exact IEEE-divide fallback.
__global__ __launch_bounds__(512) void nms_topk(
    const float* __restrict__ rois,     // [B,R,4]
    const float* __restrict__ scores,   // [B*R, C+1]
    const float* __restrict__ deltas,   // [B*R, (C+1)*4]
    const int*   __restrict__ im_hw,    // [B,2]
    u32*   __restrict__ done_cnt,       // [B]
    u64*   __restrict__ cand_key,       // [B*C, K]
    float4* __restrict__ cand_box,      // [B*C, K]
    float* __restrict__ out)            // [B, K, 6]
{
#pragma clang fp contract(off)
  const int bc = blockIdx.x;
  const int b = bc / CC, c = bc % CC;
  const int tid = threadIdx.x;
  const int lane = tid & 63, wv = tid >> 6;

  __shared__ __align__(16) char pool[42240];
  float4* box_s  = (float4*)pool;                 // 0     .. 8192
  float*  sco_s  = (float*)(pool + 8192);         // 8192  .. 10240
  u64*    keyarr = (u64*)(pool + 10240);          // 10240 .. 14336
  u64*    rmk_w  = (u64*)(pool + 14336);          // [8][64] .. 18432
  float4* kbox   = (float4*)(pool + 18432);       // 18432 .. 20032
  float*  ksc    = (float*)(pool + 20032);        // .. 20432
  float*  karea  = (float*)(pool + 20432);        // .. 20832
  __shared__ u64 supacc_arr[8];
  __shared__ int nkept_s, lastflag;

  const float fh = (float)im_hw[b * 2 + 0] - 1.0f;
  const float fw = (float)im_hw[b * 2 + 1] - 1.0f;

  // ---- hybrid bitonic sort (R8): shfl for j<64, LDS for j>=64 ----
  {
    const float sc = scores[(b * RR + tid) * (CC + 1) + (c + 1)];
    u64 v = ((u64)(~f32_sortable(sc)) << 32) | (u32)tid;  // score desc, idx asc
    const u32 t = (u32)tid;
    for (u32 kk = 2; kk <= RR; kk <<= 1) {
      for (u32 j = kk >> 1; j > 0; j >>= 1) {
        u64 p;
        if (j >= 64) {
          keyarr[t] = v;
          __syncthreads();
          p = keyarr[t ^ j];
          __syncthreads();
        } else {
          p = __shfl_xor(v, (int)j);
        }
        bool up = ((t & kk) == 0);
        bool lower = ((t & j) == 0);
        bool takemin = (up == lower);
        bool pless = (p < v);
        v = (takemin == pless) ? p : v;
      }
    }
    keyarr[t] = v;
  }
  __syncthreads();

  // ---- decode into sorted order ----
  {
    const u64 kv = keyarr[tid];
    const int r = (int)(kv & 0xFFFFFFFFull);
    const float sc = sortable_to_f32(~(u32)(kv >> 32));   // bit-exact original
    const float4 roi = *(const float4*)&rois[(b * RR + r) * 4];
    const int base = (b * RR + r) * (CC + 1) + (c + 1);
    const float4 d = *(const float4*)&deltas[base * 4];

    float w  = roi.z - roi.x;
    float h  = roi.w - roi.y;
    float cx = roi.x + 0.5f * w;
    float cy = roi.y + 0.5f * h;
    float dw = fminf(d.z, DWH_CLIP);
    float dh = fminf(d.w, DWH_CLIP);
    float pcx = d.x * w + cx;
    float pcy = d.y * h + cy;
    float pw = w * expf(dw);
    float ph = h * expf(dh);
    float hx = 0.5f * pw, hy = 0.5f * ph;
    float x1 = fminf(fmaxf(pcx - hx, 0.0f), fw);
    float y1 = fminf(fmaxf(pcy - hy, 0.0f), fh);
    float x2 = fminf(fmaxf(pcx + hx, 0.0f), fw);
    float y2 = fminf(fmaxf(pcy + hy, 0.0f), fh);

    box_s[tid] = make_float4(x1, y1, x2, y2);
    sco_s[tid] = sc;
    if (tid == 0) nkept_s = 0;
  }
  __syncthreads();

  // ---- lazy greedy NMS over chunks of 64 ----
  int nk = 0;
  for (int w = 0; w < 8 && nk < KK; ++w) {
    const float4 bxc = box_s[w * 64 + lane];
    const float ar = (bxc.z - bxc.x) * (bxc.w - bxc.y);
    const float areps = ar + 1e-9f;

    // (a) in-chunk row-mask slice: wave wv covers columns wv*8..wv*8+7
    {
      u64 myrow = 0;
      #pragma unroll
      for (int jj = 0; jj < 8; ++jj) {
        const int j = wv * 8 + jj;
        const float4 cb = box_s[w * 64 + j];              // broadcast
        const float ca = (cb.z - cb.x) * (cb.w - cb.y);
        float iw = fminf(bxc.z, cb.z) - fmaxf(bxc.x, cb.x);
        float ih = fminf(bxc.w, cb.w) - fmaxf(bxc.y, cb.y);
        iw = fmaxf(iw, 0.0f);
        ih = fmaxf(ih, 0.0f);
        const float inter = iw * ih;
        const float S = ca + areps;
        bool yes = inter * 4.3333247f > S;                // 13/3*(1-2e-6)
        const bool no = inter * 4.3333420f < S;           // 13/3*(1+2e-6)
        if (__any(!(yes || no))) {                        // ~never taken
          const float denom = ((ca + ar) - inter) + 1e-9f;  // exact ref order
          const bool pe = inter / denom > NMS_TH;
          yes = (yes || no) ? yes : pe;
        }
        myrow |= yes ? (1ull << j) : 0ull;
      }
      myrow &= ~((2ull << lane) - 1ull);                  // only cols > row
      rmk_w[wv * 64 + lane] = myrow;
    }

    // (b) suppression by previously-kept boxes, wave-strided slices
    {
      bool sup = false;
      for (int kx = wv; kx < nk; kx += 8) {
        const float4 kb = kbox[kx];                       // broadcast
        const float ka = karea[kx];
        float iw = fminf(bxc.z, kb.z) - fmaxf(bxc.x, kb.x);
        float ih = fminf(bxc.w, kb.w) - fmaxf(bxc.y, kb.y);
        iw = fmaxf(iw, 0.0f);
        ih = fmaxf(ih, 0.0f);
        const float inter = iw * ih;
        const float S = ka + areps;
        bool yes = inter * 4.3333247f > S;
        const bool no = inter * 4.3333420f < S;
        if (__any(!(yes || no))) {                        // ~never taken
          const float denom = ((ka + ar) - inter) + 1e-9f;
          const bool pe = inter / denom > NMS_TH;
          yes = (yes || no) ? yes : pe;
        }
        sup = sup || yes;
      }
      const u64 bal = __ballot(sup);
      if (lane == 0) supacc_arr[wv] = bal;
    }
    __syncthreads();

    // (c) serial scan (wave 0): scalar chain (ffs + readlane + and)
    if (wv == 0) {
      u64 sup2 = supacc_arr[0];
      #pragma unroll
      for (int ww = 1; ww < 8; ++ww) sup2 |= supacc_arr[ww];
      u64 rm = rmk_w[lane];
      #pragma unroll
      for (int ww = 1; ww < 8; ++ww) rm |= rmk_w[ww * 64 + lane];
      const u32 rlo = (u32)rm, rhi = (u32)(rm >> 32);
      u64 todo = __ballot(sco_s[w * 64 + lane] > SCORE_TH) & ~sup2;
      int nkl = nk;
      while (todo) {
        const int i = __ffsll((long long)todo) - 1;       // best remaining
        if (lane == 0) {
          const float4 kb = box_s[w * 64 + i];
          kbox[nkl] = kb;
          ksc[nkl] = sco_s[w * 64 + i];
          karea[nkl] = (kb.z - kb.x) * (kb.w - kb.y);
        }
        ++nkl;
        if (nkl >= KK) break;
        const u32 rl = (u32)__builtin_amdgcn_readlane((int)rlo, i);
        const u32 rh = (u32)__builtin_amdgcn_readlane((int)rhi, i);
        todo &= ~((2ull << i) - 1ull);                    // clear bits <= i
        todo &= ~(((u64)rh << 32) | rl);
      }
      if (lane == 0) nkept_s = nkl;
    }
    __syncthreads();
    nk = nkept_s;
  }

  // ---- emit candidates (pads unique, score = -1e9 = reference NEG) ----
  if (tid < KK) {
    const int kx = tid;
    u64 kv; float4 obx;
    if (kx < nk) {
      kv = ((u64)(~f32_sortable(ksc[kx])) << 32) | ((u64)(u32)c << 16) | (u32)kx;
      obx = kbox[kx];
    } else {
      kv = ((u64)(~f32_sortable(-1e9f)) << 32) | ((u64)(u32)c << 16) | (u32)kx;
      obx = make_float4(0.f, 0.f, 0.f, 0.f);
    }
    cand_key[bc * KK + kx] = kv;
    cand_box[bc * KK + kx] = obx;
  }

  // ---- last block per image runs the top-k ----
  __threadfence();
  if (tid == 0) {
    const u32 old = atomicAdd(&done_cnt[b], 1u);
    lastflag = (old == CC - 1) ? 1 : 0;
  }
  __syncthreads();
  if (!lastflag) return;
  __threadfence();

  // ===== top-k phase (512 threads), LDS pool re-aliased =====
  const int N = CC * KK;                 // 8000
  const u64* __restrict__ keys_g = cand_key + (size_t)b * N;
  u16* candA = (u16*)pool;               // 16000 B
  u16* candB = (u16*)(pool + 16000);     // 16000 B
  u32* whist = (u32*)(pool + 32000);     // [8][256] 8192 B
  u32* bins  = (u32*)(pool + 40192);     // 1024 B
  u64* smallkeys = (u64*)(pool + 41216); // 1024 B
  __shared__ int ncand_s, rank_s, q_s;
  __shared__ u32 cnt_s;

  if (tid == 0) { ncand_s = N; rank_s = KK - 1; }

  u16* cur = candA;
  u16* oth = candB;
  bool first = true;
  int d = 7;
  for (;;) {
    for (int t = tid; t < 8 * 256; t += 512) whist[t] = 0;
    __syncthreads();
    const int nc = first ? N : ncand_s;
    const int sh = d * 8;
    for (int t0 = 0; t0 < nc; t0 += 512) {
      const int t = t0 + tid;
      if (t < nc) {
        const int idx = first ? t : (int)cur[t];
        u32 dig = (u32)((keys_g[idx] >> sh) & 0xFF);
        atomicAdd(&whist[wv * 256 + dig], 1u);
      }
    }
    __syncthreads();
    if (tid < 256) {
      u32 s = 0;
      #pragma unroll
      for (int ww = 0; ww < 8; ++ww) s += whist[ww * 256 + tid];
      bins[tid] = s;
    }
    __syncthreads();
    if (wv == 0) {
      u32 c0 = bins[lane * 4 + 0], c1 = bins[lane * 4 + 1];
      u32 c2 = bins[lane * 4 + 2], c3 = bins[lane * 4 + 3];
      u32 lsum = c0 + c1 + c2 + c3;
      u32 incl = lsum;
      #pragma unroll
      for (int off = 1; off < 64; off <<= 1) {
        u32 v = __shfl_up(incl, off);
        if (lane >= off) incl += v;
      }
      u32 excl = incl - lsum;
      int rk = rank_s;
      u32 s0 = excl, s1 = excl + c0, s2 = s1 + c1, s3 = s2 + c2;
      int q = -1; u32 nr = 0;
      if (rk >= (int)s0 && rk < (int)(s0 + c0)) { q = lane * 4 + 0; nr = rk - s0; }
      else if (rk >= (int)s1 && rk < (int)(s1 + c1)) { q = lane * 4 + 1; nr = rk - s1; }
      else if (rk >= (int)s2 && rk < (int)(s2 + c2)) { q = lane * 4 + 2; nr = rk - s2; }
      else if (rk >= (int)s3 && rk < (int)(s3 + c3)) { q = lane * 4 + 3; nr = rk - s3; }
      if (q >= 0) { q_s = q; rank_s = (int)nr; }
    }
    if (tid == 0) cnt_s = 0;
    __syncthreads();
    const int q = q_s;
    for (int t0 = 0; t0 < nc; t0 += 512) {
      const int t = t0 + tid;
      int idx = 0; bool m = false;
      if (t < nc) {
        idx = first ? t : (int)cur[t];
        m = ((int)((keys_g[idx] >> sh) & 0xFF) == q);
      }
      u64 bal = __ballot(m);
      u32 base = 0;
      if (lane == 0 && bal) base = atomicAdd(&cnt_s, (u32)__popcll(bal));
      base = __shfl(base, 0);
      if (m) oth[base + (u32)__popcll(bal & ((1ull << lane) - 1ull))] = (u16)idx;
    }
    __syncthreads();
    if (tid == 0) ncand_s = (int)cnt_s;
    { u16* tmp = cur; cur = oth; oth = tmp; }
    first = false;
    __syncthreads();
    if (ncand_s <= 128 || d == 0) break;
    --d;
  }

  u64 T;
  const int nc2 = ncand_s;
  if (nc2 == 1) {
    T = keys_g[cur[0]];
  } else {
    if (tid < 128) smallkeys[tid] = (tid < nc2) ? keys_g[cur[tid]] : ~0ull;
    __syncthreads();
    sort128(smallkeys, tid);
    T = smallkeys[rank_s];                 // rank within candidate set
    __syncthreads();
  }

  // gather the exactly-100 keys <= T (wave-aggregated)
  if (tid == 0) cnt_s = 0;
  if (tid < 128) smallkeys[tid] = ~0ull;
  __syncthreads();
  for (int t0 = 0; t0 < N; t0 += 512) {
    const int t = t0 + tid;
    u64 kk = 0; bool m = false;
    if (t < N) { kk = keys_g[t]; m = (kk <= T); }
    u64 bal = __ballot(m);
    u32 base = 0;
    if (lane == 0 && bal) base = atomicAdd(&cnt_s, (u32)__popcll(bal));
    base = __shfl(base, 0);
    if (m) {
      u32 p = base + (u32)__popcll(bal & ((1ull << lane) - 1ull));
      if (p < 128) smallkeys[p] = kk;
    }
  }
  __syncthreads();

  sort128(smallkeys, tid);

  if (tid < KK) {
    const u64 kv = smallkeys[tid];
    const float s = sortable_to_f32(~(u32)(kv >> 32));
    float x1 = 0.f, y1 = 0.f, x2 = 0.f, y2 = 0.f, so = 0.f, cf = -1.0f;
    if (s > -5.0e8f) {                     // valid = top_s > NEG*0.5
      int cc2 = (int)((kv >> 16) & 0xFFFFull);
      int kx = (int)(kv & 0xFFFFull);
      float4 bx = cand_box[((size_t)b * CC + cc2) * KK + kx];
      x1 = bx.x; y1 = bx.y; x2 = bx.z; y2 = bx.w;
      so = s; cf = (float)cc2;
    }
    float* o = out + ((size_t)b * KK + tid) * 6;
    o[0] = x1; o[1] = y1; o[2] = x2; o[3] = y2; o[4] = so; o[5] = cf;
  }
}

extern "C" void kernel_launch(void* const* d_in, const int* in_sizes, int n_in,
                              void* d_out, int out_size, void* d_ws, size_t ws_size,
                              hipStream_t stream) {
  (void)in_sizes; (void)n_in; (void)out_size; (void)ws_size;
  const float* rois   = (const float*)d_in[0];
  const float* scores = (const float*)d_in[1];
  const float* deltas = (const float*)d_in[2];
  const int*   im_hw  = (const int*)d_in[3];

  char* ws = (char*)d_ws;
  u32*    done_cnt = (u32*)ws;                     // 16 B (page-padded)
  u64*    cand_key = (u64*)(ws + 4096);            // 4*80*100*8 = 256,000
  float4* cand_box = (float4*)(ws + 4096 + 256000);// 4*80*100*16= 512,000

  hipMemsetAsync(done_cnt, 0, BB * sizeof(u32), stream);
  nms_topk<<<BB * CC, 512, 0, stream>>>(rois, scores, deltas, im_hw,
                                        done_cnt, cand_key, cand_box,
                                        (float*)d_out);
}

// Round 11
// 64.063 us; speedup vs baseline: 2.1607x; 1.8285x over previous
//
#include <hip/hip_runtime.h>
#include <cstdint>

#define BB 4
#define RR 512
#define CC 80
#define KK 100
#define NMS_TH 0.3f
#define SCORE_TH 0.1f
#define DWH_CLIP 4.135166556742356f

typedef unsigned short u16;
typedef unsigned int u32;
typedef unsigned long long u64;

__device__ __forceinline__ u32 f32_sortable(float f) {
  u32 u = __float_as_uint(f);
  u32 mask = (u32)((int)u >> 31) | 0x80000000u;
  return u ^ mask;
}
__device__ __forceinline__ float sortable_to_f32(u32 s) {
  u32 u = (s & 0x80000000u) ? (s ^ 0x80000000u) : ~s;
  return __uint_as_float(u);
}

// Kernel 1: one block of 512 per (b,c). Fused: score-sort (LDS-hybrid
// bitonic), decode, lazy greedy NMS (per-wave rmk slices + readlane scan
// chain), emit <=100 kept candidates.
// Certain-test (validated R4-R10): q > TH <=> inter*(1+TH)/TH > ai+aj+1e-9
// in reals; band +-2e-6 >> rounding error ~3e-7; exact IEEE-divide fallback.
__global__ __launch_bounds__(512) void nms_fused(
    const float* __restrict__ rois,     // [B,R,4]
    const float* __restrict__ scores,   // [B*R, C+1]
    const float* __restrict__ deltas,   // [B*R, (C+1)*4]
    const int*   __restrict__ im_hw,    // [B,2]
    u64*   __restrict__ cand_key,       // [B*C, K]
    float4* __restrict__ cand_box)      // [B*C, K]
{
#pragma clang fp contract(off)
  const int bc = blockIdx.x;
  const int b = bc / CC, c = bc % CC;
  const int tid = threadIdx.x;
  const int lane = tid & 63, wv = tid >> 6;

  __shared__ u64    keyarr[RR];        // 4 KB (sort)
  __shared__ float4 box_s[RR];         // 8 KB sorted boxes
  __shared__ float  sco_s[RR];         // 2 KB sorted scores
  __shared__ u64    rmk_w[8 * 64];     // 4 KB per-wave row-mask slices
  __shared__ u64    supacc_arr[8];
  __shared__ float4 kbox[KK];
  __shared__ float  ksc[KK];
  __shared__ float  karea[KK];
  __shared__ int    nkept_s;

  const float fh = (float)im_hw[b * 2 + 0] - 1.0f;
  const float fw = (float)im_hw[b * 2 + 1] - 1.0f;

  // ---- hybrid bitonic sort: shfl for j<64, LDS for j>=64 ----
  {
    const float sc = scores[(b * RR + tid) * (CC + 1) + (c + 1)];
    u64 v = ((u64)(~f32_sortable(sc)) << 32) | (u32)tid;  // score desc, idx asc
    const u32 t = (u32)tid;
    for (u32 kk = 2; kk <= RR; kk <<= 1) {
      for (u32 j = kk >> 1; j > 0; j >>= 1) {
        u64 p;
        if (j >= 64) {
          keyarr[t] = v;
          __syncthreads();
          p = keyarr[t ^ j];
          __syncthreads();
        } else {
          p = __shfl_xor(v, (int)j);
        }
        bool up = ((t & kk) == 0);
        bool lower = ((t & j) == 0);
        bool takemin = (up == lower);
        bool pless = (p < v);
        v = (takemin == pless) ? p : v;
      }
    }
    keyarr[t] = v;
  }
  __syncthreads();

  // ---- decode into sorted order ----
  {
    const u64 kv = keyarr[tid];
    const int r = (int)(kv & 0xFFFFFFFFull);
    const float sc = sortable_to_f32(~(u32)(kv >> 32));   // bit-exact original
    const float4 roi = *(const float4*)&rois[(b * RR + r) * 4];
    const int base = (b * RR + r) * (CC + 1) + (c + 1);
    const float4 d = *(const float4*)&deltas[base * 4];

    float w  = roi.z - roi.x;
    float h  = roi.w - roi.y;
    float cx = roi.x + 0.5f * w;
    float cy = roi.y + 0.5f * h;
    float dw = fminf(d.z, DWH_CLIP);
    float dh = fminf(d.w, DWH_CLIP);
    float pcx = d.x * w + cx;
    float pcy = d.y * h + cy;
    float pw = w * expf(dw);
    float ph = h * expf(dh);
    float hx = 0.5f * pw, hy = 0.5f * ph;
    float x1 = fminf(fmaxf(pcx - hx, 0.0f), fw);
    float y1 = fminf(fmaxf(pcy - hy, 0.0f), fh);
    float x2 = fminf(fmaxf(pcx + hx, 0.0f), fw);
    float y2 = fminf(fmaxf(pcy + hy, 0.0f), fh);

    box_s[tid] = make_float4(x1, y1, x2, y2);
    sco_s[tid] = sc;
    if (tid == 0) nkept_s = 0;
  }
  __syncthreads();

  // ---- lazy greedy NMS over 8 chunks of 64 ----
  int nk = 0;
  for (int w = 0; w < 8 && nk < KK; ++w) {
    const float4 bxc = box_s[w * 64 + lane];
    const float ar = (bxc.z - bxc.x) * (bxc.w - bxc.y);
    const float areps = ar + 1e-9f;

    // (a) in-chunk row-mask slice: wave wv covers columns wv*8..wv*8+7
    {
      u64 myrow = 0;
      #pragma unroll
      for (int jj = 0; jj < 8; ++jj) {
        const int j = wv * 8 + jj;
        const float4 cb = box_s[w * 64 + j];              // broadcast
        const float ca = (cb.z - cb.x) * (cb.w - cb.y);
        float iw = fminf(bxc.z, cb.z) - fmaxf(bxc.x, cb.x);
        float ih = fminf(bxc.w, cb.w) - fmaxf(bxc.y, cb.y);
        iw = fmaxf(iw, 0.0f);
        ih = fmaxf(ih, 0.0f);
        const float inter = iw * ih;
        const float S = ca + areps;
        bool yes = inter * 4.3333247f > S;                // 13/3*(1-2e-6)
        const bool no = inter * 4.3333420f < S;           // 13/3*(1+2e-6)
        if (__any(!(yes || no))) {                        // ~never taken
          const float denom = ((ca + ar) - inter) + 1e-9f;  // exact ref order
          const bool pe = inter / denom > NMS_TH;
          yes = (yes || no) ? yes : pe;
        }
        myrow |= yes ? (1ull << j) : 0ull;
      }
      myrow &= ~((2ull << lane) - 1ull);                  // only cols > row
      rmk_w[wv * 64 + lane] = myrow;
    }

    // (b) suppression by previously-kept boxes, wave-strided slices
    {
      bool sup = false;
      for (int kx = wv; kx < nk; kx += 8) {
        const float4 kb = kbox[kx];                       // broadcast
        const float ka = karea[kx];
        float iw = fminf(bxc.z, kb.z) - fmaxf(bxc.x, kb.x);
        float ih = fminf(bxc.w, kb.w) - fmaxf(bxc.y, kb.y);
        iw = fmaxf(iw, 0.0f);
        ih = fmaxf(ih, 0.0f);
        const float inter = iw * ih;
        const float S = ka + areps;
        bool yes = inter * 4.3333247f > S;
        const bool no = inter * 4.3333420f < S;
        if (__any(!(yes || no))) {                        // ~never taken
          const float denom = ((ka + ar) - inter) + 1e-9f;
          const bool pe = inter / denom > NMS_TH;
          yes = (yes || no) ? yes : pe;
        }
        sup = sup || yes;
      }
      const u64 bal = __ballot(sup);
      if (lane == 0) supacc_arr[wv] = bal;
    }
    __syncthreads();

    // (c) serial scan (wave 0): scalar chain (ffs + readlane + and)
    if (wv == 0) {
      u64 sup2 = supacc_arr[0];
      #pragma unroll
      for (int ww = 1; ww < 8; ++ww) sup2 |= supacc_arr[ww];
      u64 rm = rmk_w[lane];
      #pragma unroll
      for (int ww = 1; ww < 8; ++ww) rm |= rmk_w[ww * 64 + lane];
      const u32 rlo = (u32)rm, rhi = (u32)(rm >> 32);
      u64 todo = __ballot(sco_s[w * 64 + lane] > SCORE_TH) & ~sup2;
      int nkl = nk;
      while (todo) {
        const int i = __ffsll((long long)todo) - 1;       // best remaining
        if (lane == 0) {
          const float4 kb = box_s[w * 64 + i];
          kbox[nkl] = kb;
          ksc[nkl] = sco_s[w * 64 + i];
          karea[nkl] = (kb.z - kb.x) * (kb.w - kb.y);
        }
        ++nkl;
        if (nkl >= KK) break;
        const u32 rl = (u32)__builtin_amdgcn_readlane((int)rlo, i);
        const u32 rh = (u32)__builtin_amdgcn_readlane((int)rhi, i);
        todo &= ~((2ull << i) - 1ull);                    // clear bits <= i
        todo &= ~(((u64)rh << 32) | rl);
      }
      if (lane == 0) nkept_s = nkl;
    }
    __syncthreads();
    nk = nkept_s;
  }

  // ---- emit candidates (pads unique, score = -1e9 = reference NEG) ----
  if (tid < KK) {
    const int kx = tid;
    u64 kv; float4 obx;
    if (kx < nk) {
      kv = ((u64)(~f32_sortable(ksc[kx])) << 32) | ((u64)(u32)c << 16) | (u32)kx;
      obx = kbox[kx];
    } else {
      kv = ((u64)(~f32_sortable(-1e9f)) << 32) | ((u64)(u32)c << 16) | (u32)kx;
      obx = make_float4(0.f, 0.f, 0.f, 0.f);
    }
    cand_key[bc * KK + kx] = kv;
    cand_box[bc * KK + kx] = obx;
  }
}

__device__ __forceinline__ void sort128(u64* smallkeys, int tid) {
  u64 v = (tid < 128) ? smallkeys[tid] : ~0ull;
  const u32 t = (u32)tid;
  for (u32 kk = 2; kk <= 128; kk <<= 1) {
    for (u32 j = kk >> 1; j > 0; j >>= 1) {
      if (j >= 64) {
        if (tid < 128) smallkeys[t] = v;
        __syncthreads();
        u64 p = (tid < 128) ? smallkeys[t ^ j] : ~0ull;
        __syncthreads();
        if (tid < 128) {
          bool up = ((t & kk) == 0);
          bool lower = ((t & j) == 0);
          bool takemin = (up == lower);
          bool pless = (p < v);
          v = (takemin == pless) ? p : v;
        }
      } else if (tid < 128) {
        u64 p = __shfl_xor(v, (int)j);
        bool up = ((t & kk) == 0);
        bool lower = ((t & j) == 0);
        bool takemin = (up == lower);
        bool pless = (p < v);
        v = (takemin == pless) ? p : v;
      }
    }
  }
  if (tid < 128) smallkeys[t] = v;
  __syncthreads();
}

// Kernel 2: one block per image. Radix-select rank-99 key T over 8000 unique
// keys; break to a 128-sort once <=128 candidates remain; gather the
// exactly-100 keys <= T, sort, write [K,6].
__global__ __launch_bounds__(1024) void topk_select(
    const u64* __restrict__ cand_key,    // [B, C*K]
    const float4* __restrict__ cand_box, // [B*C, K]
    float* __restrict__ out)             // [B, K, 6]
{
  const int b = blockIdx.x;
  const int tid = threadIdx.x;
  const int lane = tid & 63, wv = tid >> 6;
  const int N = CC * KK;                 // 8000
  const u64* __restrict__ keys_g = cand_key + (size_t)b * N;

  __shared__ u16 candA[CC * KK];         // 16 KB
  __shared__ u16 candB[CC * KK];         // 16 KB
  __shared__ u32 whist[16][256];         // 16 KB
  __shared__ u32 bins[256];
  __shared__ u64 smallkeys[128];
  __shared__ int ncand_s, rank_s, q_s;
  __shared__ u32 cnt_s;

  if (tid == 0) { ncand_s = N; rank_s = KK - 1; }

  u16* cur = candA;
  u16* oth = candB;
  bool first = true;
  int d = 7;
  for (;;) {
    for (int t = tid; t < 16 * 256; t += 1024) ((u32*)whist)[t] = 0;
    __syncthreads();
    const int nc = first ? N : ncand_s;
    const int sh = d * 8;
    for (int t0 = 0; t0 < nc; t0 += 1024) {
      const int t = t0 + tid;
      if (t < nc) {
        const int idx = first ? t : (int)cur[t];
        u32 dig = (u32)((keys_g[idx] >> sh) & 0xFF);
        atomicAdd(&whist[wv][dig], 1u);
      }
    }
    __syncthreads();
    if (tid < 256) {
      u32 s = 0;
      #pragma unroll
      for (int w = 0; w < 16; ++w) s += whist[w][tid];
      bins[tid] = s;
    }
    __syncthreads();
    if (wv == 0) {
      u32 c0 = bins[lane * 4 + 0], c1 = bins[lane * 4 + 1];
      u32 c2 = bins[lane * 4 + 2], c3 = bins[lane * 4 + 3];
      u32 lsum = c0 + c1 + c2 + c3;
      u32 incl = lsum;
      #pragma unroll
      for (int off = 1; off < 64; off <<= 1) {
        u32 v = __shfl_up(incl, off);
        if (lane >= off) incl += v;
      }
      u32 excl = incl - lsum;
      int rk = rank_s;
      u32 s0 = excl, s1 = excl + c0, s2 = s1 + c1, s3 = s2 + c2;
      int q = -1; u32 nr = 0;
      if (rk >= (int)s0 && rk < (int)(s0 + c0)) { q = lane * 4 + 0; nr = rk - s0; }
      else if (rk >= (int)s1 && rk < (int)(s1 + c1)) { q = lane * 4 + 1; nr = rk - s1; }
      else if (rk >= (int)s2 && rk < (int)(s2 + c2)) { q = lane * 4 + 2; nr = rk - s2; }
      else if (rk >= (int)s3 && rk < (int)(s3 + c3)) { q = lane * 4 + 3; nr = rk - s3; }
      if (q >= 0) { q_s = q; rank_s = (int)nr; }
    }
    if (tid == 0) cnt_s = 0;
    __syncthreads();
    const int q = q_s;
    for (int t0 = 0; t0 < nc; t0 += 1024) {
      const int t = t0 + tid;
      int idx = 0; bool m = false;
      if (t < nc) {
        idx = first ? t : (int)cur[t];
        m = ((int)((keys_g[idx] >> sh) & 0xFF) == q);
      }
      u64 bal = __ballot(m);
      u32 base = 0;
      if (lane == 0 && bal) base = atomicAdd(&cnt_s, (u32)__popcll(bal));
      base = __shfl(base, 0);
      if (m) oth[base + (u32)__popcll(bal & ((1ull << lane) - 1ull))] = (u16)idx;
    }
    __syncthreads();
    if (tid == 0) ncand_s = (int)cnt_s;
    { u16* tmp = cur; cur = oth; oth = tmp; }
    first = false;
    __syncthreads();
    if (ncand_s <= 128 || d == 0) break;
    --d;
  }

  u64 T;
  const int nc2 = ncand_s;
  if (nc2 == 1) {
    T = keys_g[cur[0]];
  } else {
    if (tid < 128) smallkeys[tid] = (tid < nc2) ? keys_g[cur[tid]] : ~0ull;
    __syncthreads();
    sort128(smallkeys, tid);
    T = smallkeys[rank_s];                 // rank within candidate set
    __syncthreads();
  }

  // gather the exactly-100 keys <= T (wave-aggregated)
  if (tid == 0) cnt_s = 0;
  if (tid < 128) smallkeys[tid] = ~0ull;
  __syncthreads();
  for (int t0 = 0; t0 < N; t0 += 1024) {
    const int t = t0 + tid;
    u64 k = 0; bool m = false;
    if (t < N) { k = keys_g[t]; m = (k <= T); }
    u64 bal = __ballot(m);
    u32 base = 0;
    if (lane == 0 && bal) base = atomicAdd(&cnt_s, (u32)__popcll(bal));
    base = __shfl(base, 0);
    if (m) {
      u32 p = base + (u32)__popcll(bal & ((1ull << lane) - 1ull));
      if (p < 128) smallkeys[p] = k;
    }
  }
  __syncthreads();

  sort128(smallkeys, tid);

  if (tid < KK) {
    const u64 kv = smallkeys[tid];
    const float s = sortable_to_f32(~(u32)(kv >> 32));
    float x1 = 0.f, y1 = 0.f, x2 = 0.f, y2 = 0.f, so = 0.f, cf = -1.0f;
    if (s > -5.0e8f) {                     // valid = top_s > NEG*0.5
      int c = (int)((kv >> 16) & 0xFFFFull);
      int k = (int)(kv & 0xFFFFull);
      float4 bx = cand_box[((size_t)b * CC + c) * KK + k];
      x1 = bx.x; y1 = bx.y; x2 = bx.z; y2 = bx.w;
      so = s; cf = (float)c;
    }
    float* o = out + ((size_t)b * KK + tid) * 6;
    o[0] = x1; o[1] = y1; o[2] = x2; o[3] = y2; o[4] = so; o[5] = cf;
  }
}

extern "C" void kernel_launch(void* const* d_in, const int* in_sizes, int n_in,
                              void* d_out, int out_size, void* d_ws, size_t ws_size,
                              hipStream_t stream) {
  (void)in_sizes; (void)n_in; (void)out_size; (void)ws_size;
  const float* rois   = (const float*)d_in[0];
  const float* scores = (const float*)d_in[1];
  const float* deltas = (const float*)d_in[2];
  const int*   im_hw  = (const int*)d_in[3];

  char* ws = (char*)d_ws;
  u64*    cand_key = (u64*)ws;                     // 4*80*100*8 = 256,000
  float4* cand_box = (float4*)(ws + 256000);       // 4*80*100*16= 512,000

  nms_fused<<<BB * CC, 512, 0, stream>>>(rois, scores, deltas, im_hw,
                                         cand_key, cand_box);
  topk_select<<<BB, 1024, 0, stream>>>(cand_key, cand_box, (float*)d_out);
}